// Round 13
// baseline (133.641 us; speedup 1.0000x reference)
//
#include <hip/hip_runtime.h>
#include <hip/hip_bf16.h>
#include <math.h>

#define NTOK 1152
#define DIM 512
#define NQKV 1536
#define DHEAD 64
#define NBH 16
#define TEXTN 128
#define IMGLEN 1024
#define SEG (NBH * NTOK * DHEAD)  // 1179648
#define STF 68
#define TSTATE_F (NBH * IMGLEN * STF)
#define LPAD 40
#define KTSZ (NBH * TEXTN * DHEAD)  // 131072

typedef __attribute__((ext_vector_type(8))) short bf16x8;
typedef __attribute__((ext_vector_type(4))) float f32x4;

__device__ __forceinline__ ushort f2bf(float f) {
    unsigned u = __float_as_uint(f);
    unsigned r = (u + 0x7FFFu + ((u >> 16) & 1u)) >> 16;  // RNE
    return (ushort)r;
}
__device__ __forceinline__ float bf2f(ushort u) {
    return __uint_as_float(((unsigned)u) << 16);
}

// ---------------- P1: x -> x_hi/x_lo bf16 ---------------------------------
__global__ __launch_bounds__(256) void prep_x_k(const float* __restrict__ X,
                                                ushort* __restrict__ xhi,
                                                ushort* __restrict__ xlo) {
    int i = (blockIdx.x * 256 + threadIdx.x) * 4;
    float4 v = *(const float4*)(X + i);
    ushort4 h, l;
    h.x = f2bf(v.x); l.x = f2bf(v.x - bf2f(h.x));
    h.y = f2bf(v.y); l.y = f2bf(v.y - bf2f(h.y));
    h.z = f2bf(v.z); l.z = f2bf(v.z - bf2f(h.z));
    h.w = f2bf(v.w); l.w = f2bf(v.w - bf2f(h.w));
    *(ushort4*)(xhi + i) = h;
    *(ushort4*)(xlo + i) = l;
}

// ---------------- P2: W[K][N] -> Wt_hi/lo[N][K] bf16 ----------------------
__global__ __launch_bounds__(256) void prep_wt_k(const float* __restrict__ W,
                                                 ushort* __restrict__ thi,
                                                 ushort* __restrict__ tlo,
                                                 int K, int N) {
    __shared__ float tile[32][33];
    const int bx = blockIdx.x, by = blockIdx.y;
    const int c = threadIdx.x & 31, r8 = threadIdx.x >> 5;
#pragma unroll
    for (int i = 0; i < 4; ++i) {
        int rr = r8 + i * 8;
        tile[rr][c] = W[(size_t)(by * 32 + rr) * N + bx * 32 + c];
    }
    __syncthreads();
#pragma unroll
    for (int i = 0; i < 4; ++i) {
        int rr = r8 + i * 8;
        float v = tile[c][rr];
        size_t o = (size_t)(bx * 32 + rr) * K + by * 32 + c;
        ushort h = f2bf(v);
        thi[o] = h;
        tlo[o] = f2bf(v - bf2f(h));
    }
}

// ---------------- K1: qkv GEMM via split-bf16 MFMA ------------------------
__global__ __launch_bounds__(256) void gemm_qkv_mfma(const ushort* __restrict__ xhi,
                                                     const ushort* __restrict__ xlo,
                                                     const ushort* __restrict__ wthi,
                                                     const ushort* __restrict__ wtlo,
                                                     float* __restrict__ qh,
                                                     float* __restrict__ kh,
                                                     float* __restrict__ vh,
                                                     ushort* __restrict__ qhi,
                                                     ushort* __restrict__ qlo,
                                                     ushort* __restrict__ kthi,
                                                     ushort* __restrict__ ktlo,
                                                     ushort* __restrict__ vthi,
                                                     ushort* __restrict__ vtlo) {
    __shared__ __align__(16) ushort Ah[128 * LPAD], Al[128 * LPAD];
    __shared__ __align__(16) ushort Bh[64 * LPAD], Bl[64 * LPAD];
    const int tid = threadIdx.x;
    const int lane = tid & 63;
    const int w = tid >> 6;
    const int wm = w >> 1, wn = w & 1;
    const int row0 = blockIdx.y * 128;
    const int col0 = blockIdx.x * 64;

    f32x4 acc[4][2];
#pragma unroll
    for (int a = 0; a < 4; ++a)
#pragma unroll
        for (int b = 0; b < 2; ++b) acc[a][b] = (f32x4){0.f, 0.f, 0.f, 0.f};

    const int arow = tid >> 1;
    const int akb = (tid & 1) * 16;
    const int brow = tid >> 2;
    const int bkb = (tid & 3) * 8;
    const int kf = (lane >> 4) * 8;
    const int lr = lane & 15;

    for (int k0 = 0; k0 < DIM; k0 += 32) {
        {
            const size_t g = (size_t)(row0 + arow) * DIM + k0 + akb;
            *(bf16x8*)&Ah[arow * LPAD + akb] = *(const bf16x8*)(xhi + g);
            *(bf16x8*)&Ah[arow * LPAD + akb + 8] = *(const bf16x8*)(xhi + g + 8);
            *(bf16x8*)&Al[arow * LPAD + akb] = *(const bf16x8*)(xlo + g);
            *(bf16x8*)&Al[arow * LPAD + akb + 8] = *(const bf16x8*)(xlo + g + 8);
        }
        {
            const size_t g = (size_t)(col0 + brow) * DIM + k0 + bkb;
            *(bf16x8*)&Bh[brow * LPAD + bkb] = *(const bf16x8*)(wthi + g);
            *(bf16x8*)&Bl[brow * LPAD + bkb] = *(const bf16x8*)(wtlo + g);
        }
        __syncthreads();
        bf16x8 ah[4], al[4], bh[2], bl[2];
#pragma unroll
        for (int mi = 0; mi < 4; ++mi) {
            int rr = wm * 64 + mi * 16 + lr;
            ah[mi] = *(const bf16x8*)&Ah[rr * LPAD + kf];
            al[mi] = *(const bf16x8*)&Al[rr * LPAD + kf];
        }
#pragma unroll
        for (int ni = 0; ni < 2; ++ni) {
            int rr = wn * 32 + ni * 16 + lr;
            bh[ni] = *(const bf16x8*)&Bh[rr * LPAD + kf];
            bl[ni] = *(const bf16x8*)&Bl[rr * LPAD + kf];
        }
#pragma unroll
        for (int mi = 0; mi < 4; ++mi)
#pragma unroll
            for (int ni = 0; ni < 2; ++ni) {
                acc[mi][ni] = __builtin_amdgcn_mfma_f32_16x16x32_bf16(ah[mi], bh[ni], acc[mi][ni], 0, 0, 0);
                acc[mi][ni] = __builtin_amdgcn_mfma_f32_16x16x32_bf16(ah[mi], bl[ni], acc[mi][ni], 0, 0, 0);
                acc[mi][ni] = __builtin_amdgcn_mfma_f32_16x16x32_bf16(al[mi], bh[ni], acc[mi][ni], 0, 0, 0);
            }
        __syncthreads();
    }

    const int which = col0 >> 9;
    const int hh = (col0 & 511) >> 6;
    const float scale = (which == 0) ? 0.125f : 1.f;
    float* dst = (which == 0) ? qh : ((which == 1) ? kh : vh);
#pragma unroll
    for (int mi = 0; mi < 4; ++mi)
#pragma unroll
        for (int ni = 0; ni < 2; ++ni)
#pragma unroll
            for (int j = 0; j < 4; ++j) {
                int r = row0 + wm * 64 + mi * 16 + (lane >> 4) * 4 + j;
                int b_i = r / NTOK, tok = r - b_i * NTOK;
                int d = wn * 32 + ni * 16 + (lane & 15);
                int bhi = b_i * 8 + hh;
                float val = acc[mi][ni][j] * scale;
                dst[((size_t)bhi * NTOK + tok) * DHEAD + d] = val;
                if (which == 0) {
                    size_t qo = ((size_t)bhi * NTOK + tok) * DHEAD + d;
                    ushort h2 = f2bf(val);
                    qhi[qo] = h2;
                    qlo[qo] = f2bf(val - bf2f(h2));
                } else if (tok >= IMGLEN) {
                    int tr = tok - IMGLEN;
                    ushort h2 = f2bf(val);
                    ushort l2 = f2bf(val - bf2f(h2));
                    if (which == 1) {
                        size_t ko = ((size_t)bhi * TEXTN + tr) * DHEAD + d;
                        kthi[ko] = h2; ktlo[ko] = l2;
                    } else {
                        size_t vo = ((size_t)bhi * DHEAD + d) * TEXTN + tr;
                        vthi[vo] = h2; vtlo[vo] = l2;
                    }
                }
            }
}

// ---------------- K2: text-key attention via MFMA (all 1152 rows) ---------
__global__ __launch_bounds__(256) void attn_text_mfma(const ushort* __restrict__ qhi,
                                                      const ushort* __restrict__ qlo,
                                                      const ushort* __restrict__ kthi,
                                                      const ushort* __restrict__ ktlo,
                                                      const ushort* __restrict__ vthi,
                                                      const ushort* __restrict__ vtlo,
                                                      ushort* __restrict__ ahi,
                                                      ushort* __restrict__ alo,
                                                      float* __restrict__ tstate) {
    __shared__ __align__(16) ushort Phi[4][16][136];
    __shared__ __align__(16) ushort Plo[4][16][136];
    const int bh = blockIdx.x / 18;
    const int tile = blockIdx.x % 18;
    const int wave = threadIdx.x >> 6;
    const int lane = threadIdx.x & 63;
    const int lr = lane & 15, lg = lane >> 4;
    const int kf = lg * 8;
    const int qrow0 = tile * 64 + wave * 16;
    const int tok0 = (tile < 2 ? 1024 + tile * 64 : tile * 64) + wave * 16;

    bf16x8 qah[2], qal[2];
    {
        const size_t qb = ((size_t)bh * NTOK + tok0 + lr) * DHEAD;
#pragma unroll
        for (int c = 0; c < 2; ++c) {
            qah[c] = *(const bf16x8*)(qhi + qb + c * 32 + kf);
            qal[c] = *(const bf16x8*)(qlo + qb + c * 32 + kf);
        }
    }
    f32x4 s[8];
#pragma unroll
    for (int t = 0; t < 8; ++t) s[t] = (f32x4){0.f, 0.f, 0.f, 0.f};
#pragma unroll
    for (int t = 0; t < 8; ++t) {
        const size_t kb = ((size_t)bh * TEXTN + t * 16 + lr) * DHEAD;
#pragma unroll
        for (int c = 0; c < 2; ++c) {
            bf16x8 kbh = *(const bf16x8*)(kthi + kb + c * 32 + kf);
            bf16x8 kbl = *(const bf16x8*)(ktlo + kb + c * 32 + kf);
            s[t] = __builtin_amdgcn_mfma_f32_16x16x32_bf16(qah[c], kbh, s[t], 0, 0, 0);
            s[t] = __builtin_amdgcn_mfma_f32_16x16x32_bf16(qah[c], kbl, s[t], 0, 0, 0);
            s[t] = __builtin_amdgcn_mfma_f32_16x16x32_bf16(qal[c], kbh, s[t], 0, 0, 0);
        }
    }
    float mx[4], sm[4];
#pragma unroll
    for (int r = 0; r < 4; ++r) {
        float v = s[0][r];
#pragma unroll
        for (int t = 1; t < 8; ++t) v = fmaxf(v, s[t][r]);
        mx[r] = v;
    }
#pragma unroll
    for (int msk = 1; msk <= 8; msk <<= 1)
#pragma unroll
        for (int r = 0; r < 4; ++r) mx[r] = fmaxf(mx[r], __shfl_xor(mx[r], msk));
#pragma unroll
    for (int r = 0; r < 4; ++r) sm[r] = 0.f;
#pragma unroll
    for (int t = 0; t < 8; ++t)
#pragma unroll
        for (int r = 0; r < 4; ++r) {
            float p = __expf(s[t][r] - mx[r]);
            s[t][r] = p;
            sm[r] += p;
        }
#pragma unroll
    for (int msk = 1; msk <= 8; msk <<= 1)
#pragma unroll
        for (int r = 0; r < 4; ++r) sm[r] += __shfl_xor(sm[r], msk);
#pragma unroll
    for (int t = 0; t < 8; ++t)
#pragma unroll
        for (int r = 0; r < 4; ++r) {
            float p = s[t][r];
            ushort h = f2bf(p);
            Phi[wave][lg * 4 + r][t * 16 + lr] = h;
            Plo[wave][lg * 4 + r][t * 16 + lr] = f2bf(p - bf2f(h));
        }
    __syncthreads();
    f32x4 o[4];
#pragma unroll
    for (int dt = 0; dt < 4; ++dt) o[dt] = (f32x4){0.f, 0.f, 0.f, 0.f};
#pragma unroll
    for (int c = 0; c < 4; ++c) {
        bf16x8 pah = *(const bf16x8*)&Phi[wave][lr][c * 32 + kf];
        bf16x8 pal = *(const bf16x8*)&Plo[wave][lr][c * 32 + kf];
#pragma unroll
        for (int dt = 0; dt < 4; ++dt) {
            const size_t vb = ((size_t)bh * DHEAD + dt * 16 + lr) * TEXTN + c * 32 + kf;
            bf16x8 vbh = *(const bf16x8*)(vthi + vb);
            bf16x8 vbl = *(const bf16x8*)(vtlo + vb);
            o[dt] = __builtin_amdgcn_mfma_f32_16x16x32_bf16(pah, vbh, o[dt], 0, 0, 0);
            o[dt] = __builtin_amdgcn_mfma_f32_16x16x32_bf16(pah, vbl, o[dt], 0, 0, 0);
            o[dt] = __builtin_amdgcn_mfma_f32_16x16x32_bf16(pal, vbh, o[dt], 0, 0, 0);
        }
    }
    if (tile < 2) {
#pragma unroll
        for (int r = 0; r < 4; ++r) {
            const int row = qrow0 + lg * 4 + r;
            const float inv = 1.f / sm[r];
            const size_t base = ((size_t)bh * NTOK + row) * DHEAD;
#pragma unroll
            for (int dt = 0; dt < 4; ++dt) {
                float v = o[dt][r] * inv;
                ushort h = f2bf(v);
                ahi[base + dt * 16 + lr] = h;
                alo[base + dt * 16 + lr] = f2bf(v - bf2f(h));
            }
        }
    } else {
#pragma unroll
        for (int r = 0; r < 4; ++r) {
            const int imgq = qrow0 - TEXTN + lg * 4 + r;
            float* st = tstate + ((size_t)bh * IMGLEN + imgq) * STF;
#pragma unroll
            for (int dt = 0; dt < 4; ++dt) st[dt * 16 + lr] = o[dt][r];
            if (lr == 0) { st[64] = mx[r]; st[65] = sm[r]; }
        }
    }
}

// ---------------- K3: img local 25-slot part, 8-wave split ----------------
// Block = 512 threads = 8 waves, 64 queries (lane = query).
// Dots: wave w covers channel-eighth [8w, 8w+8) over ALL taps (full q[64]
// indexing -- scramble spans all channels). PV: wave w covers channel
// quarter (w&3) over tap range (w<4 ? taps 0..12 : taps 13..24).
// PV reduction: 4 sequential deterministic rounds into 2 LDS buffers.
// LDS: sdb[8][64][26] (53.2KB) aliased with pob[2][64][68] (34.8KB).
template <int W8>
__device__ inline void loc_dots8(const float* __restrict__ kimg, int y, int x,
                                 const float (&q)[64], float (&sd)[25]) {
#pragma unroll
    for (int t = 0; t < 25; ++t) {
        const int ny = y + t / 5 - 2;
        const int nx = x + t % 5 - 2;
        if (ny >= 0 && ny < 32 && nx >= 0 && nx < 32) {
            const float* kp = kimg + (size_t)(ny * 32 + nx) * DHEAD + W8 * 8;
            float4 k0 = *(const float4*)kp;
            float4 k1 = *(const float4*)(kp + 4);
            float ke[8] = {k0.x, k0.y, k0.z, k0.w, k1.x, k1.y, k1.z, k1.w};
#pragma unroll
            for (int e = 0; e < 8; ++e) {
                const int d = W8 * 8 + e;
                const int id2 = d * 25 + t;
                sd[id2 >> 6] += q[id2 & 63] * ke[e];
            }
        }
    }
}

template <int W, int T0, int T1>
__device__ inline void loc_pvr(const float* __restrict__ vimg, int y, int x,
                               const float (&p)[25], float (&po)[64]) {
#pragma unroll
    for (int t = T0; t < T1; ++t) {
        const int ny = y + t / 5 - 2;
        const int nx = x + t % 5 - 2;
        if (ny >= 0 && ny < 32 && nx >= 0 && nx < 32) {
            const float* vp = vimg + (size_t)(ny * 32 + nx) * DHEAD + W * 16;
#pragma unroll
            for (int g = 0; g < 4; ++g) {
                float4 vv = *(const float4*)(vp + g * 4);
                float ve[4] = {vv.x, vv.y, vv.z, vv.w};
#pragma unroll
                for (int e = 0; e < 4; ++e) {
                    const int d = W * 16 + g * 4 + e;
                    const int id2 = d * 25 + t;
                    po[id2 & 63] += p[id2 >> 6] * ve[e];
                }
            }
        }
    }
}

__global__ __launch_bounds__(512) void attn_img_k(const float* __restrict__ qh,
                                                  const float* __restrict__ kh,
                                                  const float* __restrict__ vh,
                                                  ushort* __restrict__ ahi,
                                                  ushort* __restrict__ alo,
                                                  const float* __restrict__ tstate) {
    __shared__ __align__(16) float smem[8 * 64 * 26];  // 53248 B, aliased
    float (*sdb)[64][26] = reinterpret_cast<float (*)[64][26]>(smem);   // [8]
    float (*pob)[64][68] = reinterpret_cast<float (*)[64][68]>(smem);   // [2]
    const int bh = blockIdx.x >> 4;
    const int qtile = (blockIdx.x & 15) << 6;
    const int wave = threadIdx.x >> 6;
    const int lane = threadIdx.x & 63;
    const int qq = qtile + lane;
    const int y = qq >> 5, x = qq & 31;
    const float* kimg = kh + (size_t)(bh * NTOK + TEXTN) * DHEAD;
    const float* vimg = vh + (size_t)(bh * NTOK + TEXTN) * DHEAD;
    const float* st = tstate + ((size_t)(bh * IMGLEN + qq)) * STF;

    // ---- pass 1: channel-eighth scrambled dots (all 8 waves) ----
    float sd[25];
#pragma unroll
    for (int j = 0; j < 25; ++j) sd[j] = 0.f;
    {
        float q[64];
        const float* qp = qh + ((size_t)(bh * NTOK + TEXTN + qq)) * DHEAD;
#pragma unroll
        for (int g = 0; g < 16; ++g) {
            float4 v4 = *(const float4*)(qp + g * 4);
            q[g * 4] = v4.x; q[g * 4 + 1] = v4.y; q[g * 4 + 2] = v4.z; q[g * 4 + 3] = v4.w;
        }
        switch (wave) {
            case 0: loc_dots8<0>(kimg, y, x, q, sd); break;
            case 1: loc_dots8<1>(kimg, y, x, q, sd); break;
            case 2: loc_dots8<2>(kimg, y, x, q, sd); break;
            case 3: loc_dots8<3>(kimg, y, x, q, sd); break;
            case 4: loc_dots8<4>(kimg, y, x, q, sd); break;
            case 5: loc_dots8<5>(kimg, y, x, q, sd); break;
            case 6: loc_dots8<6>(kimg, y, x, q, sd); break;
            default: loc_dots8<7>(kimg, y, x, q, sd); break;
        }
    }
#pragma unroll
    for (int j = 0; j < 25; ++j) sdb[wave][lane][j] = sd[j];
    __syncthreads();

    // ---- pass 2: all waves: sum 8 partials, mask, merge with text state --
    float p[25];
#pragma unroll
    for (int j = 0; j < 25; ++j)
        p[j] = ((sdb[0][lane][j] + sdb[1][lane][j]) + (sdb[2][lane][j] + sdb[3][lane][j])) +
               ((sdb[4][lane][j] + sdb[5][lane][j]) + (sdb[6][lane][j] + sdb[7][lane][j]));
    float m = st[64], l = st[65];
    float mloc = -1e30f;
#pragma unroll
    for (int j = 0; j < 25; ++j) {
        const int my = y + j / 5 - 2;
        const int mx = x + j % 5 - 2;
        bool inb = (my >= 0 && my < 32 && mx >= 0 && mx < 32);
        bool keep = inb ? (qq <= my * 32 + mx) : true;
        p[j] = keep ? p[j] : -1e30f;
        mloc = fmaxf(mloc, p[j]);
    }
    const float M = fmaxf(m, mloc);
    const float cc = __expf(m - M);
    l *= cc;
#pragma unroll
    for (int j = 0; j < 25; ++j) {
        p[j] = __expf(p[j] - M);
        l += p[j];
    }
    const float inv = 1.f / l;

    // ---- pass 3: PV, quarter x tap-half per wave ----
    float po[64];
#pragma unroll
    for (int o = 0; o < 64; ++o) po[o] = 0.f;
    switch (wave) {
        case 0: loc_pvr<0, 0, 13>(vimg, y, x, p, po); break;
        case 1: loc_pvr<1, 0, 13>(vimg, y, x, p, po); break;
        case 2: loc_pvr<2, 0, 13>(vimg, y, x, p, po); break;
        case 3: loc_pvr<3, 0, 13>(vimg, y, x, p, po); break;
        case 4: loc_pvr<0, 13, 25>(vimg, y, x, p, po); break;
        case 5: loc_pvr<1, 13, 25>(vimg, y, x, p, po); break;
        case 6: loc_pvr<2, 13, 25>(vimg, y, x, p, po); break;
        default: loc_pvr<3, 13, 25>(vimg, y, x, p, po); break;
    }
    __syncthreads();  // all sdb reads done; pob aliases sdb

    // ---- pass 4: deterministic 4-round reduction into 2 buffers ----
    if (wave < 2) {
#pragma unroll
        for (int o = 0; o < 64; ++o) pob[wave][lane][o] = po[o];
    }
    __syncthreads();
    if (wave >= 2 && wave < 4) {
#pragma unroll
        for (int o = 0; o < 64; ++o) pob[wave - 2][lane][o] += po[o];
    }
    __syncthreads();
    if (wave >= 4 && wave < 6) {
#pragma unroll
        for (int o = 0; o < 64; ++o) pob[wave - 4][lane][o] += po[o];
    }
    __syncthreads();
    if (wave >= 6) {
#pragma unroll
        for (int o = 0; o < 64; ++o) pob[wave - 6][lane][o] += po[o];
    }
    __syncthreads();

    // ---- pass 5: waves 0..3 finalize their d-quarter ----
    if (wave < 4) {
        const float* stq = st + wave * 16;
        size_t base = ((size_t)(bh * NTOK + TEXTN + qq)) * DHEAD + wave * 16;
#pragma unroll
        for (int g = 0; g < 4; ++g) {
            float4 tv = *(const float4*)(stq + g * 4);
            float4 a0 = *(const float4*)&pob[0][lane][wave * 16 + g * 4];
            float4 a1 = *(const float4*)&pob[1][lane][wave * 16 + g * 4];
            float v0 = (a0.x + a1.x + cc * tv.x) * inv;
            float v1 = (a0.y + a1.y + cc * tv.y) * inv;
            float v2 = (a0.z + a1.z + cc * tv.z) * inv;
            float v3 = (a0.w + a1.w + cc * tv.w) * inv;
            ushort4 oh, ol;
            oh.x = f2bf(v0); ol.x = f2bf(v0 - bf2f(oh.x));
            oh.y = f2bf(v1); ol.y = f2bf(v1 - bf2f(oh.y));
            oh.z = f2bf(v2); ol.z = f2bf(v2 - bf2f(oh.z));
            oh.w = f2bf(v3); ol.w = f2bf(v3 - bf2f(oh.w));
            *(ushort4*)(ahi + base + g * 4) = oh;
            *(ushort4*)(alo + base + g * 4) = ol;
        }
    }
}

// ---------------- K4: out GEMM via split-bf16 MFMA ------------------------
__global__ __launch_bounds__(256) void gemm_out_mfma(const ushort* __restrict__ ahi,
                                                     const ushort* __restrict__ alo,
                                                     const ushort* __restrict__ wthi,
                                                     const ushort* __restrict__ wtlo,
                                                     const float* __restrict__ bias,
                                                     float* __restrict__ Y) {
    __shared__ __align__(16) ushort Ah[128 * LPAD], Al[128 * LPAD];
    __shared__ __align__(16) ushort Bh[64 * LPAD], Bl[64 * LPAD];
    const int tid = threadIdx.x;
    const int lane = tid & 63;
    const int w = tid >> 6;
    const int wm = w >> 1, wn = w & 1;
    const int row0 = blockIdx.y * 128;
    const int col0 = blockIdx.x * 64;

    f32x4 acc[4][2];
#pragma unroll
    for (int a = 0; a < 4; ++a)
#pragma unroll
        for (int b = 0; b < 2; ++b) acc[a][b] = (f32x4){0.f, 0.f, 0.f, 0.f};

    const int arow = tid >> 1;
    const int akb = (tid & 1) * 16;
    const int brow = tid >> 2;
    const int bkb = (tid & 3) * 8;
    const int kf = (lane >> 4) * 8;
    const int lr = lane & 15;

    const int ar = row0 + arow;
    const int a_bi = ar / NTOK;
    const int a_tok = ar - a_bi * NTOK;

    for (int k0 = 0; k0 < DIM; k0 += 32) {
        {
            const int kg = k0 + akb;
            const int hh = kg >> 6, d0 = kg & 63;
            const size_t g = ((size_t)(a_bi * 8 + hh) * NTOK + a_tok) * DHEAD + d0;
            *(bf16x8*)&Ah[arow * LPAD + akb] = *(const bf16x8*)(ahi + g);
            *(bf16x8*)&Ah[arow * LPAD + akb + 8] = *(const bf16x8*)(ahi + g + 8);
            *(bf16x8*)&Al[arow * LPAD + akb] = *(const bf16x8*)(alo + g);
            *(bf16x8*)&Al[arow * LPAD + akb + 8] = *(const bf16x8*)(alo + g + 8);
        }
        {
            const size_t g = (size_t)(col0 + brow) * DIM + k0 + bkb;
            *(bf16x8*)&Bh[brow * LPAD + bkb] = *(const bf16x8*)(wthi + g);
            *(bf16x8*)&Bl[brow * LPAD + bkb] = *(const bf16x8*)(wtlo + g);
        }
        __syncthreads();
        bf16x8 ah[4], al[4], bh[2], bl[2];
#pragma unroll
        for (int mi = 0; mi < 4; ++mi) {
            int rr = wm * 64 + mi * 16 + lr;
            ah[mi] = *(const bf16x8*)&Ah[rr * LPAD + kf];
            al[mi] = *(const bf16x8*)&Al[rr * LPAD + kf];
        }
#pragma unroll
        for (int ni = 0; ni < 2; ++ni) {
            int rr = wn * 32 + ni * 16 + lr;
            bh[ni] = *(const bf16x8*)&Bh[rr * LPAD + kf];
            bl[ni] = *(const bf16x8*)&Bl[rr * LPAD + kf];
        }
#pragma unroll
        for (int mi = 0; mi < 4; ++mi)
#pragma unroll
            for (int ni = 0; ni < 2; ++ni) {
                acc[mi][ni] = __builtin_amdgcn_mfma_f32_16x16x32_bf16(ah[mi], bh[ni], acc[mi][ni], 0, 0, 0);
                acc[mi][ni] = __builtin_amdgcn_mfma_f32_16x16x32_bf16(ah[mi], bl[ni], acc[mi][ni], 0, 0, 0);
                acc[mi][ni] = __builtin_amdgcn_mfma_f32_16x16x32_bf16(al[mi], bh[ni], acc[mi][ni], 0, 0, 0);
            }
        __syncthreads();
    }

#pragma unroll
    for (int mi = 0; mi < 4; ++mi)
#pragma unroll
        for (int ni = 0; ni < 2; ++ni) {
            int cidx = col0 + wn * 32 + ni * 16 + (lane & 15);
            float bv = bias[cidx];
#pragma unroll
            for (int j = 0; j < 4; ++j) {
                int r = row0 + wm * 64 + mi * 16 + (lane >> 4) * 4 + j;
                Y[(size_t)r * DIM + cidx] = acc[mi][ni][j] + bv;
            }
        }
}

extern "C" void kernel_launch(void* const* d_in, const int* in_sizes, int n_in,
                              void* d_out, int out_size, void* d_ws, size_t ws_size,
                              hipStream_t stream) {
    const float* x = (const float*)d_in[0];
    const float* w_qkv = (const float*)d_in[1];
    const float* w_out = (const float*)d_in[2];
    const float* b_out = (const float*)d_in[3];
    float* Y = (float*)d_out;
    float* ws = (float*)d_ws;
    float* qh = ws;
    float* kh = ws + (size_t)SEG;
    float* vh = ws + 2 * (size_t)SEG;
    float* tstate = ws + 3 * (size_t)SEG;
    ushort* xhi = (ushort*)(ws + 3 * (size_t)SEG + TSTATE_F);
    ushort* xlo = xhi + (size_t)SEG;
    ushort* ahi = xhi;  // alias: x dead after gemm_qkv; attn written after
    ushort* alo = xlo;
    ushort* wqthi = xlo + (size_t)SEG;
    ushort* wqtlo = wqthi + (size_t)DIM * NQKV;
    ushort* wothi = wqtlo + (size_t)DIM * NQKV;
    ushort* wotlo = wothi + (size_t)DIM * DIM;
    ushort* qhi = wotlo + (size_t)DIM * DIM;
    ushort* qlo = qhi + (size_t)SEG;
    ushort* kthi = qlo + (size_t)SEG;
    ushort* ktlo = kthi + (size_t)KTSZ;
    ushort* vthi = ktlo + (size_t)KTSZ;
    ushort* vtlo = vthi + (size_t)KTSZ;

    hipLaunchKernelGGL(prep_x_k, dim3(SEG / 1024), dim3(256), 0, stream, x, xhi, xlo);
    hipLaunchKernelGGL(prep_wt_k, dim3(NQKV / 32, DIM / 32), dim3(256), 0, stream,
                       w_qkv, wqthi, wqtlo, DIM, NQKV);
    hipLaunchKernelGGL(prep_wt_k, dim3(DIM / 32, DIM / 32), dim3(256), 0, stream,
                       w_out, wothi, wotlo, DIM, DIM);
    hipLaunchKernelGGL(gemm_qkv_mfma, dim3(NQKV / 64, 2304 / 128), dim3(256), 0, stream,
                       xhi, xlo, wqthi, wqtlo, qh, kh, vh,
                       qhi, qlo, kthi, ktlo, vthi, vtlo);
    hipLaunchKernelGGL(attn_text_mfma, dim3(NBH * 18), dim3(256), 0, stream,
                       qhi, qlo, kthi, ktlo, vthi, vtlo, ahi, alo, tstate);
    hipLaunchKernelGGL(attn_img_k, dim3(NBH * 16), dim3(512), 0, stream,
                       qh, kh, vh, ahi, alo, tstate);
    hipLaunchKernelGGL(gemm_out_mfma, dim3(DIM / 64, 2304 / 128), dim3(256), 0, stream,
                       ahi, alo, wothi, wotlo, b_out, Y);
}

// Round 14
// 131.271 us; speedup vs baseline: 1.0181x; 1.0181x over previous
//
#include <hip/hip_runtime.h>
#include <hip/hip_bf16.h>
#include <math.h>

#define NTOK 1152
#define DIM 512
#define NQKV 1536
#define DHEAD 64
#define NBH 16
#define TEXTN 128
#define IMGLEN 1024
#define SEG (NBH * NTOK * DHEAD)  // 1179648
#define STF 68
#define TSTATE_F (NBH * IMGLEN * STF)
#define LPAD 40
#define KTSZ (NBH * TEXTN * DHEAD)  // 131072

typedef __attribute__((ext_vector_type(8))) short bf16x8;
typedef __attribute__((ext_vector_type(4))) float f32x4;

__device__ __forceinline__ ushort f2bf(float f) {
    unsigned u = __float_as_uint(f);
    unsigned r = (u + 0x7FFFu + ((u >> 16) & 1u)) >> 16;  // RNE
    return (ushort)r;
}
__device__ __forceinline__ float bf2f(ushort u) {
    return __uint_as_float(((unsigned)u) << 16);
}

// ---------------- P1: x -> x_hi/x_lo bf16 ---------------------------------
__global__ __launch_bounds__(256) void prep_x_k(const float* __restrict__ X,
                                                ushort* __restrict__ xhi,
                                                ushort* __restrict__ xlo) {
    int i = (blockIdx.x * 256 + threadIdx.x) * 4;
    float4 v = *(const float4*)(X + i);
    ushort4 h, l;
    h.x = f2bf(v.x); l.x = f2bf(v.x - bf2f(h.x));
    h.y = f2bf(v.y); l.y = f2bf(v.y - bf2f(h.y));
    h.z = f2bf(v.z); l.z = f2bf(v.z - bf2f(h.z));
    h.w = f2bf(v.w); l.w = f2bf(v.w - bf2f(h.w));
    *(ushort4*)(xhi + i) = h;
    *(ushort4*)(xlo + i) = l;
}

// ---------------- P2: W[K][N] -> Wt_hi/lo[N][K] bf16 ----------------------
__global__ __launch_bounds__(256) void prep_wt_k(const float* __restrict__ W,
                                                 ushort* __restrict__ thi,
                                                 ushort* __restrict__ tlo,
                                                 int K, int N) {
    __shared__ float tile[32][33];
    const int bx = blockIdx.x, by = blockIdx.y;
    const int c = threadIdx.x & 31, r8 = threadIdx.x >> 5;
#pragma unroll
    for (int i = 0; i < 4; ++i) {
        int rr = r8 + i * 8;
        tile[rr][c] = W[(size_t)(by * 32 + rr) * N + bx * 32 + c];
    }
    __syncthreads();
#pragma unroll
    for (int i = 0; i < 4; ++i) {
        int rr = r8 + i * 8;
        float v = tile[c][rr];
        size_t o = (size_t)(bx * 32 + rr) * K + by * 32 + c;
        ushort h = f2bf(v);
        thi[o] = h;
        tlo[o] = f2bf(v - bf2f(h));
    }
}

// ---------------- K1: qkv GEMM via split-bf16 MFMA ------------------------
__global__ __launch_bounds__(256) void gemm_qkv_mfma(const ushort* __restrict__ xhi,
                                                     const ushort* __restrict__ xlo,
                                                     const ushort* __restrict__ wthi,
                                                     const ushort* __restrict__ wtlo,
                                                     float* __restrict__ qh,
                                                     float* __restrict__ kh,
                                                     float* __restrict__ vh,
                                                     ushort* __restrict__ qhi,
                                                     ushort* __restrict__ qlo,
                                                     ushort* __restrict__ kthi,
                                                     ushort* __restrict__ ktlo,
                                                     ushort* __restrict__ vthi,
                                                     ushort* __restrict__ vtlo) {
    __shared__ __align__(16) ushort Ah[128 * LPAD], Al[128 * LPAD];
    __shared__ __align__(16) ushort Bh[64 * LPAD], Bl[64 * LPAD];
    const int tid = threadIdx.x;
    const int lane = tid & 63;
    const int w = tid >> 6;
    const int wm = w >> 1, wn = w & 1;
    const int row0 = blockIdx.y * 128;
    const int col0 = blockIdx.x * 64;

    f32x4 acc[4][2];
#pragma unroll
    for (int a = 0; a < 4; ++a)
#pragma unroll
        for (int b = 0; b < 2; ++b) acc[a][b] = (f32x4){0.f, 0.f, 0.f, 0.f};

    const int arow = tid >> 1;
    const int akb = (tid & 1) * 16;
    const int brow = tid >> 2;
    const int bkb = (tid & 3) * 8;
    const int kf = (lane >> 4) * 8;
    const int lr = lane & 15;

    for (int k0 = 0; k0 < DIM; k0 += 32) {
        {
            const size_t g = (size_t)(row0 + arow) * DIM + k0 + akb;
            *(bf16x8*)&Ah[arow * LPAD + akb] = *(const bf16x8*)(xhi + g);
            *(bf16x8*)&Ah[arow * LPAD + akb + 8] = *(const bf16x8*)(xhi + g + 8);
            *(bf16x8*)&Al[arow * LPAD + akb] = *(const bf16x8*)(xlo + g);
            *(bf16x8*)&Al[arow * LPAD + akb + 8] = *(const bf16x8*)(xlo + g + 8);
        }
        {
            const size_t g = (size_t)(col0 + brow) * DIM + k0 + bkb;
            *(bf16x8*)&Bh[brow * LPAD + bkb] = *(const bf16x8*)(wthi + g);
            *(bf16x8*)&Bl[brow * LPAD + bkb] = *(const bf16x8*)(wtlo + g);
        }
        __syncthreads();
        bf16x8 ah[4], al[4], bh[2], bl[2];
#pragma unroll
        for (int mi = 0; mi < 4; ++mi) {
            int rr = wm * 64 + mi * 16 + lr;
            ah[mi] = *(const bf16x8*)&Ah[rr * LPAD + kf];
            al[mi] = *(const bf16x8*)&Al[rr * LPAD + kf];
        }
#pragma unroll
        for (int ni = 0; ni < 2; ++ni) {
            int rr = wn * 32 + ni * 16 + lr;
            bh[ni] = *(const bf16x8*)&Bh[rr * LPAD + kf];
            bl[ni] = *(const bf16x8*)&Bl[rr * LPAD + kf];
        }
#pragma unroll
        for (int mi = 0; mi < 4; ++mi)
#pragma unroll
            for (int ni = 0; ni < 2; ++ni) {
                acc[mi][ni] = __builtin_amdgcn_mfma_f32_16x16x32_bf16(ah[mi], bh[ni], acc[mi][ni], 0, 0, 0);
                acc[mi][ni] = __builtin_amdgcn_mfma_f32_16x16x32_bf16(ah[mi], bl[ni], acc[mi][ni], 0, 0, 0);
                acc[mi][ni] = __builtin_amdgcn_mfma_f32_16x16x32_bf16(al[mi], bh[ni], acc[mi][ni], 0, 0, 0);
            }
        __syncthreads();
    }

    const int which = col0 >> 9;
    const int hh = (col0 & 511) >> 6;
    const float scale = (which == 0) ? 0.125f : 1.f;
    float* dst = (which == 0) ? qh : ((which == 1) ? kh : vh);
#pragma unroll
    for (int mi = 0; mi < 4; ++mi)
#pragma unroll
        for (int ni = 0; ni < 2; ++ni)
#pragma unroll
            for (int j = 0; j < 4; ++j) {
                int r = row0 + wm * 64 + mi * 16 + (lane >> 4) * 4 + j;
                int b_i = r / NTOK, tok = r - b_i * NTOK;
                int d = wn * 32 + ni * 16 + (lane & 15);
                int bhi = b_i * 8 + hh;
                float val = acc[mi][ni][j] * scale;
                dst[((size_t)bhi * NTOK + tok) * DHEAD + d] = val;
                if (which == 0) {
                    size_t qo = ((size_t)bhi * NTOK + tok) * DHEAD + d;
                    ushort h2 = f2bf(val);
                    qhi[qo] = h2;
                    qlo[qo] = f2bf(val - bf2f(h2));
                } else if (tok >= IMGLEN) {
                    int tr = tok - IMGLEN;
                    ushort h2 = f2bf(val);
                    ushort l2 = f2bf(val - bf2f(h2));
                    if (which == 1) {
                        size_t ko = ((size_t)bhi * TEXTN + tr) * DHEAD + d;
                        kthi[ko] = h2; ktlo[ko] = l2;
                    } else {
                        size_t vo = ((size_t)bhi * DHEAD + d) * TEXTN + tr;
                        vthi[vo] = h2; vtlo[vo] = l2;
                    }
                }
            }
}

// ---------------- K2: text-key attention via MFMA (all 1152 rows) ---------
__global__ __launch_bounds__(256) void attn_text_mfma(const ushort* __restrict__ qhi,
                                                      const ushort* __restrict__ qlo,
                                                      const ushort* __restrict__ kthi,
                                                      const ushort* __restrict__ ktlo,
                                                      const ushort* __restrict__ vthi,
                                                      const ushort* __restrict__ vtlo,
                                                      ushort* __restrict__ ahi,
                                                      ushort* __restrict__ alo,
                                                      float* __restrict__ tstate) {
    __shared__ __align__(16) ushort Phi[4][16][136];
    __shared__ __align__(16) ushort Plo[4][16][136];
    const int bh = blockIdx.x / 18;
    const int tile = blockIdx.x % 18;
    const int wave = threadIdx.x >> 6;
    const int lane = threadIdx.x & 63;
    const int lr = lane & 15, lg = lane >> 4;
    const int kf = lg * 8;
    const int qrow0 = tile * 64 + wave * 16;
    const int tok0 = (tile < 2 ? 1024 + tile * 64 : tile * 64) + wave * 16;

    bf16x8 qah[2], qal[2];
    {
        const size_t qb = ((size_t)bh * NTOK + tok0 + lr) * DHEAD;
#pragma unroll
        for (int c = 0; c < 2; ++c) {
            qah[c] = *(const bf16x8*)(qhi + qb + c * 32 + kf);
            qal[c] = *(const bf16x8*)(qlo + qb + c * 32 + kf);
        }
    }
    f32x4 s[8];
#pragma unroll
    for (int t = 0; t < 8; ++t) s[t] = (f32x4){0.f, 0.f, 0.f, 0.f};
#pragma unroll
    for (int t = 0; t < 8; ++t) {
        const size_t kb = ((size_t)bh * TEXTN + t * 16 + lr) * DHEAD;
#pragma unroll
        for (int c = 0; c < 2; ++c) {
            bf16x8 kbh = *(const bf16x8*)(kthi + kb + c * 32 + kf);
            bf16x8 kbl = *(const bf16x8*)(ktlo + kb + c * 32 + kf);
            s[t] = __builtin_amdgcn_mfma_f32_16x16x32_bf16(qah[c], kbh, s[t], 0, 0, 0);
            s[t] = __builtin_amdgcn_mfma_f32_16x16x32_bf16(qah[c], kbl, s[t], 0, 0, 0);
            s[t] = __builtin_amdgcn_mfma_f32_16x16x32_bf16(qal[c], kbh, s[t], 0, 0, 0);
        }
    }
    float mx[4], sm[4];
#pragma unroll
    for (int r = 0; r < 4; ++r) {
        float v = s[0][r];
#pragma unroll
        for (int t = 1; t < 8; ++t) v = fmaxf(v, s[t][r]);
        mx[r] = v;
    }
#pragma unroll
    for (int msk = 1; msk <= 8; msk <<= 1)
#pragma unroll
        for (int r = 0; r < 4; ++r) mx[r] = fmaxf(mx[r], __shfl_xor(mx[r], msk));
#pragma unroll
    for (int r = 0; r < 4; ++r) sm[r] = 0.f;
#pragma unroll
    for (int t = 0; t < 8; ++t)
#pragma unroll
        for (int r = 0; r < 4; ++r) {
            float p = __expf(s[t][r] - mx[r]);
            s[t][r] = p;
            sm[r] += p;
        }
#pragma unroll
    for (int msk = 1; msk <= 8; msk <<= 1)
#pragma unroll
        for (int r = 0; r < 4; ++r) sm[r] += __shfl_xor(sm[r], msk);
#pragma unroll
    for (int t = 0; t < 8; ++t)
#pragma unroll
        for (int r = 0; r < 4; ++r) {
            float p = s[t][r];
            ushort h = f2bf(p);
            Phi[wave][lg * 4 + r][t * 16 + lr] = h;
            Plo[wave][lg * 4 + r][t * 16 + lr] = f2bf(p - bf2f(h));
        }
    __syncthreads();
    f32x4 o[4];
#pragma unroll
    for (int dt = 0; dt < 4; ++dt) o[dt] = (f32x4){0.f, 0.f, 0.f, 0.f};
#pragma unroll
    for (int c = 0; c < 4; ++c) {
        bf16x8 pah = *(const bf16x8*)&Phi[wave][lr][c * 32 + kf];
        bf16x8 pal = *(const bf16x8*)&Plo[wave][lr][c * 32 + kf];
#pragma unroll
        for (int dt = 0; dt < 4; ++dt) {
            const size_t vb = ((size_t)bh * DHEAD + dt * 16 + lr) * TEXTN + c * 32 + kf;
            bf16x8 vbh = *(const bf16x8*)(vthi + vb);
            bf16x8 vbl = *(const bf16x8*)(vtlo + vb);
            o[dt] = __builtin_amdgcn_mfma_f32_16x16x32_bf16(pah, vbh, o[dt], 0, 0, 0);
            o[dt] = __builtin_amdgcn_mfma_f32_16x16x32_bf16(pah, vbl, o[dt], 0, 0, 0);
            o[dt] = __builtin_amdgcn_mfma_f32_16x16x32_bf16(pal, vbh, o[dt], 0, 0, 0);
        }
    }
    if (tile < 2) {
#pragma unroll
        for (int r = 0; r < 4; ++r) {
            const int row = qrow0 + lg * 4 + r;
            const float inv = 1.f / sm[r];
            const size_t base = ((size_t)bh * NTOK + row) * DHEAD;
#pragma unroll
            for (int dt = 0; dt < 4; ++dt) {
                float v = o[dt][r] * inv;
                ushort h = f2bf(v);
                ahi[base + dt * 16 + lr] = h;
                alo[base + dt * 16 + lr] = f2bf(v - bf2f(h));
            }
        }
    } else {
#pragma unroll
        for (int r = 0; r < 4; ++r) {
            const int imgq = qrow0 - TEXTN + lg * 4 + r;
            float* st = tstate + ((size_t)bh * IMGLEN + imgq) * STF;
#pragma unroll
            for (int dt = 0; dt < 4; ++dt) st[dt * 16 + lr] = o[dt][r];
            if (lr == 0) { st[64] = mx[r]; st[65] = sm[r]; }
        }
    }
}

// ---------------- K3: img local 25-slot part, LDS-staged K/V --------------
// Block = 512 threads = 8 waves, 64 queries (lane = query). K/V windows
// (6 rows x 32 px x 64 ch = 48KB each) staged coalesced into LDS with a
// 16B-block XOR swizzle (blk' = blk ^ (px&7)) so the 256B-stride gather
// reads are bank-spread. q bounced through LDS (aliases sdb; barrier).
// Dots: wave w = channel-eighth; PV: wave quarter x tap-half; deterministic
// LDS reductions as before.
template <int W8>
__device__ inline void loc_dots8_lds(const float* __restrict__ Kl, int yloc, int x, int y,
                                     const float (&q)[64], float (&sd)[25]) {
#pragma unroll
    for (int t = 0; t < 25; ++t) {
        const int ny = y + t / 5 - 2;
        const int nx = x + t % 5 - 2;
        if (ny >= 0 && ny < 32 && nx >= 0 && nx < 32) {
            const int px = (yloc + t / 5) * 32 + nx;
            const float* base = Kl + px * 64;
            float4 k0 = *(const float4*)(base + (((2 * W8) ^ (px & 7)) << 2));
            float4 k1 = *(const float4*)(base + (((2 * W8 + 1) ^ (px & 7)) << 2));
            float ke[8] = {k0.x, k0.y, k0.z, k0.w, k1.x, k1.y, k1.z, k1.w};
#pragma unroll
            for (int e = 0; e < 8; ++e) {
                const int d = W8 * 8 + e;
                const int id2 = d * 25 + t;
                sd[id2 >> 6] += q[id2 & 63] * ke[e];
            }
        }
    }
}

template <int W, int T0, int T1>
__device__ inline void loc_pvr_lds(const float* __restrict__ Vl, int yloc, int x, int y,
                                   const float (&pp)[25], float (&po)[64]) {
#pragma unroll
    for (int t = T0; t < T1; ++t) {
        const int ny = y + t / 5 - 2;
        const int nx = x + t % 5 - 2;
        if (ny >= 0 && ny < 32 && nx >= 0 && nx < 32) {
            const int px = (yloc + t / 5) * 32 + nx;
            const float* base = Vl + px * 64;
#pragma unroll
            for (int g = 0; g < 4; ++g) {
                float4 vv = *(const float4*)(base + (((4 * W + g) ^ (px & 7)) << 2));
                float ve[4] = {vv.x, vv.y, vv.z, vv.w};
#pragma unroll
                for (int e = 0; e < 4; ++e) {
                    const int d = W * 16 + g * 4 + e;
                    const int id2 = d * 25 + t;
                    po[id2 & 63] += pp[id2 >> 6] * ve[e];
                }
            }
        }
    }
}

__global__ __launch_bounds__(512, 1) void attn_img_k(const float* __restrict__ qh,
                                                     const float* __restrict__ kh,
                                                     const float* __restrict__ vh,
                                                     ushort* __restrict__ ahi,
                                                     ushort* __restrict__ alo,
                                                     const float* __restrict__ tstate) {
    __shared__ __align__(16) float smem[8 * 64 * 26];  // 53248 B: qbuf then sdb; pob aliases
    __shared__ __align__(16) float Kl[192 * 64];       // 49152 B
    __shared__ __align__(16) float Vl[192 * 64];       // 49152 B
    float (*sdb)[64][26] = reinterpret_cast<float (*)[64][26]>(smem);   // [8]
    float (*pob)[64][68] = reinterpret_cast<float (*)[64][68]>(smem);   // [2]
    const int bh = blockIdx.x >> 4;
    const int qtile = (blockIdx.x & 15) << 6;
    const int yr0 = qtile >> 5;  // first query row; staged rows yr0-2..yr0+3
    const int wave = threadIdx.x >> 6;
    const int lane = threadIdx.x & 63;
    const int qq = qtile + lane;
    const int y = qq >> 5, x = qq & 31;
    const int yloc = lane >> 5;
    const float* kimg = kh + (size_t)(bh * NTOK + TEXTN) * DHEAD;
    const float* vimg = vh + (size_t)(bh * NTOK + TEXTN) * DHEAD;
    const float* st = tstate + ((size_t)(bh * IMGLEN + qq)) * STF;

    // ---- stage K/V windows (swizzled) + q tile (into qbuf = smem) ----
#pragma unroll
    for (int i = 0; i < 6; ++i) {
        int flat = threadIdx.x + i * 512;  // 0..3071
        int px = flat >> 4, b = flat & 15;
        int gy = yr0 - 2 + (px >> 5), gx = px & 31;
        if (gy >= 0 && gy < 32) {
            size_t off = ((size_t)(gy * 32 + gx)) * DHEAD + b * 4;
            int dsto = px * 64 + ((b ^ (px & 7)) << 2);
            *(float4*)&Kl[dsto] = *(const float4*)(kimg + off);
            *(float4*)&Vl[dsto] = *(const float4*)(vimg + off);
        }
    }
    {
        const float* qbase = qh + ((size_t)(bh * NTOK + TEXTN + qtile)) * DHEAD;
#pragma unroll
        for (int i = 0; i < 2; ++i) {
            int flat = threadIdx.x + i * 512;  // 0..1023
            int px = flat >> 4, b = flat & 15;
            *(float4*)&smem[px * 64 + ((b ^ (px & 7)) << 2)] =
                *(const float4*)(qbase + (size_t)px * DHEAD + b * 4);
        }
    }
    __syncthreads();

    // ---- q LDS -> regs (then barrier: sdb aliases qbuf) ----
    float q[64];
#pragma unroll
    for (int b = 0; b < 16; ++b) {
        float4 v = *(const float4*)&smem[lane * 64 + ((b ^ (lane & 7)) << 2)];
        q[b * 4] = v.x; q[b * 4 + 1] = v.y; q[b * 4 + 2] = v.z; q[b * 4 + 3] = v.w;
    }
    __syncthreads();

    // ---- pass 1: channel-eighth scrambled dots from Kl ----
    float sd[25];
#pragma unroll
    for (int j = 0; j < 25; ++j) sd[j] = 0.f;
    switch (wave) {
        case 0: loc_dots8_lds<0>(Kl, yloc, x, y, q, sd); break;
        case 1: loc_dots8_lds<1>(Kl, yloc, x, y, q, sd); break;
        case 2: loc_dots8_lds<2>(Kl, yloc, x, y, q, sd); break;
        case 3: loc_dots8_lds<3>(Kl, yloc, x, y, q, sd); break;
        case 4: loc_dots8_lds<4>(Kl, yloc, x, y, q, sd); break;
        case 5: loc_dots8_lds<5>(Kl, yloc, x, y, q, sd); break;
        case 6: loc_dots8_lds<6>(Kl, yloc, x, y, q, sd); break;
        default: loc_dots8_lds<7>(Kl, yloc, x, y, q, sd); break;
    }
#pragma unroll
    for (int j = 0; j < 25; ++j) sdb[wave][lane][j] = sd[j];
    __syncthreads();

    // ---- pass 2: sum 8 partials; mask; merge with text state ----
    float p[25];
#pragma unroll
    for (int j = 0; j < 25; ++j)
        p[j] = ((sdb[0][lane][j] + sdb[1][lane][j]) + (sdb[2][lane][j] + sdb[3][lane][j])) +
               ((sdb[4][lane][j] + sdb[5][lane][j]) + (sdb[6][lane][j] + sdb[7][lane][j]));
    float m = st[64], l = st[65];
    float mloc = -1e30f;
#pragma unroll
    for (int j = 0; j < 25; ++j) {
        const int my = y + j / 5 - 2;
        const int mx2 = x + j % 5 - 2;
        bool inb = (my >= 0 && my < 32 && mx2 >= 0 && mx2 < 32);
        bool keep = inb ? (qq <= my * 32 + mx2) : true;
        p[j] = keep ? p[j] : -1e30f;
        mloc = fmaxf(mloc, p[j]);
    }
    const float M = fmaxf(m, mloc);
    const float cc = __expf(m - M);
    l *= cc;
#pragma unroll
    for (int j = 0; j < 25; ++j) {
        p[j] = __expf(p[j] - M);
        l += p[j];
    }
    const float inv = 1.f / l;

    // ---- pass 3: PV, quarter x tap-half per wave, from Vl ----
    float po[64];
#pragma unroll
    for (int o = 0; o < 64; ++o) po[o] = 0.f;
    switch (wave) {
        case 0: loc_pvr_lds<0, 0, 13>(Vl, yloc, x, y, p, po); break;
        case 1: loc_pvr_lds<1, 0, 13>(Vl, yloc, x, y, p, po); break;
        case 2: loc_pvr_lds<2, 0, 13>(Vl, yloc, x, y, p, po); break;
        case 3: loc_pvr_lds<3, 0, 13>(Vl, yloc, x, y, p, po); break;
        case 4: loc_pvr_lds<0, 13, 25>(Vl, yloc, x, y, p, po); break;
        case 5: loc_pvr_lds<1, 13, 25>(Vl, yloc, x, y, p, po); break;
        case 6: loc_pvr_lds<2, 13, 25>(Vl, yloc, x, y, p, po); break;
        default: loc_pvr_lds<3, 13, 25>(Vl, yloc, x, y, p, po); break;
    }
    __syncthreads();  // all sdb reads done; pob aliases sdb

    // ---- pass 4: deterministic 4-round reduction into 2 buffers ----
    if (wave < 2) {
#pragma unroll
        for (int o = 0; o < 64; ++o) pob[wave][lane][o] = po[o];
    }
    __syncthreads();
    if (wave >= 2 && wave < 4) {
#pragma unroll
        for (int o = 0; o < 64; ++o) pob[wave - 2][lane][o] += po[o];
    }
    __syncthreads();
    if (wave >= 4 && wave < 6) {
#pragma unroll
        for (int o = 0; o < 64; ++o) pob[wave - 4][lane][o] += po[o];
    }
    __syncthreads();
    if (wave >= 6) {
#pragma unroll
        for (int o = 0; o < 64; ++o) pob[wave - 6][lane][o] += po[o];
    }
    __syncthreads();

    // ---- pass 5: waves 0..3 finalize their d-quarter ----
    if (wave < 4) {
        const float* stq = st + wave * 16;
        size_t base = ((size_t)(bh * NTOK + TEXTN + qq)) * DHEAD + wave * 16;
#pragma unroll
        for (int g = 0; g < 4; ++g) {
            float4 tv = *(const float4*)(stq + g * 4);
            float4 a0 = *(const float4*)&pob[0][lane][wave * 16 + g * 4];
            float4 a1 = *(const float4*)&pob[1][lane][wave * 16 + g * 4];
            float v0 = (a0.x + a1.x + cc * tv.x) * inv;
            float v1 = (a0.y + a1.y + cc * tv.y) * inv;
            float v2 = (a0.z + a1.z + cc * tv.z) * inv;
            float v3 = (a0.w + a1.w + cc * tv.w) * inv;
            ushort4 oh, ol;
            oh.x = f2bf(v0); ol.x = f2bf(v0 - bf2f(oh.x));
            oh.y = f2bf(v1); ol.y = f2bf(v1 - bf2f(oh.y));
            oh.z = f2bf(v2); ol.z = f2bf(v2 - bf2f(oh.z));
            oh.w = f2bf(v3); ol.w = f2bf(v3 - bf2f(oh.w));
            *(ushort4*)(ahi + base + g * 4) = oh;
            *(ushort4*)(alo + base + g * 4) = ol;
        }
    }
}

// ---------------- K4: out GEMM via split-bf16 MFMA ------------------------
__global__ __launch_bounds__(256) void gemm_out_mfma(const ushort* __restrict__ ahi,
                                                     const ushort* __restrict__ alo,
                                                     const ushort* __restrict__ wthi,
                                                     const ushort* __restrict__ wtlo,
                                                     const float* __restrict__ bias,
                                                     float* __restrict__ Y) {
    __shared__ __align__(16) ushort Ah[128 * LPAD], Al[128 * LPAD];
    __shared__ __align__(16) ushort Bh[64 * LPAD], Bl[64 * LPAD];
    const int tid = threadIdx.x;
    const int lane = tid & 63;
    const int w = tid >> 6;
    const int wm = w >> 1, wn = w & 1;
    const int row0 = blockIdx.y * 128;
    const int col0 = blockIdx.x * 64;

    f32x4 acc[4][2];
#pragma unroll
    for (int a = 0; a < 4; ++a)
#pragma unroll
        for (int b = 0; b < 2; ++b) acc[a][b] = (f32x4){0.f, 0.f, 0.f, 0.f};

    const int arow = tid >> 1;
    const int akb = (tid & 1) * 16;
    const int brow = tid >> 2;
    const int bkb = (tid & 3) * 8;
    const int kf = (lane >> 4) * 8;
    const int lr = lane & 15;

    const int ar = row0 + arow;
    const int a_bi = ar / NTOK;
    const int a_tok = ar - a_bi * NTOK;

    for (int k0 = 0; k0 < DIM; k0 += 32) {
        {
            const int kg = k0 + akb;
            const int hh = kg >> 6, d0 = kg & 63;
            const size_t g = ((size_t)(a_bi * 8 + hh) * NTOK + a_tok) * DHEAD + d0;
            *(bf16x8*)&Ah[arow * LPAD + akb] = *(const bf16x8*)(ahi + g);
            *(bf16x8*)&Ah[arow * LPAD + akb + 8] = *(const bf16x8*)(ahi + g + 8);
            *(bf16x8*)&Al[arow * LPAD + akb] = *(const bf16x8*)(alo + g);
            *(bf16x8*)&Al[arow * LPAD + akb + 8] = *(const bf16x8*)(alo + g + 8);
        }
        {
            const size_t g = (size_t)(col0 + brow) * DIM + k0 + bkb;
            *(bf16x8*)&Bh[brow * LPAD + bkb] = *(const bf16x8*)(wthi + g);
            *(bf16x8*)&Bl[brow * LPAD + bkb] = *(const bf16x8*)(wtlo + g);
        }
        __syncthreads();
        bf16x8 ah[4], al[4], bh[2], bl[2];
#pragma unroll
        for (int mi = 0; mi < 4; ++mi) {
            int rr = wm * 64 + mi * 16 + lr;
            ah[mi] = *(const bf16x8*)&Ah[rr * LPAD + kf];
            al[mi] = *(const bf16x8*)&Al[rr * LPAD + kf];
        }
#pragma unroll
        for (int ni = 0; ni < 2; ++ni) {
            int rr = wn * 32 + ni * 16 + lr;
            bh[ni] = *(const bf16x8*)&Bh[rr * LPAD + kf];
            bl[ni] = *(const bf16x8*)&Bl[rr * LPAD + kf];
        }
#pragma unroll
        for (int mi = 0; mi < 4; ++mi)
#pragma unroll
            for (int ni = 0; ni < 2; ++ni) {
                acc[mi][ni] = __builtin_amdgcn_mfma_f32_16x16x32_bf16(ah[mi], bh[ni], acc[mi][ni], 0, 0, 0);
                acc[mi][ni] = __builtin_amdgcn_mfma_f32_16x16x32_bf16(ah[mi], bl[ni], acc[mi][ni], 0, 0, 0);
                acc[mi][ni] = __builtin_amdgcn_mfma_f32_16x16x32_bf16(al[mi], bh[ni], acc[mi][ni], 0, 0, 0);
            }
        __syncthreads();
    }

#pragma unroll
    for (int mi = 0; mi < 4; ++mi)
#pragma unroll
        for (int ni = 0; ni < 2; ++ni) {
            int cidx = col0 + wn * 32 + ni * 16 + (lane & 15);
            float bv = bias[cidx];
#pragma unroll
            for (int j = 0; j < 4; ++j) {
                int r = row0 + wm * 64 + mi * 16 + (lane >> 4) * 4 + j;
                Y[(size_t)r * DIM + cidx] = acc[mi][ni][j] + bv;
            }
        }
}

extern "C" void kernel_launch(void* const* d_in, const int* in_sizes, int n_in,
                              void* d_out, int out_size, void* d_ws, size_t ws_size,
                              hipStream_t stream) {
    const float* x = (const float*)d_in[0];
    const float* w_qkv = (const float*)d_in[1];
    const float* w_out = (const float*)d_in[2];
    const float* b_out = (const float*)d_in[3];
    float* Y = (float*)d_out;
    float* ws = (float*)d_ws;
    float* qh = ws;
    float* kh = ws + (size_t)SEG;
    float* vh = ws + 2 * (size_t)SEG;
    float* tstate = ws + 3 * (size_t)SEG;
    ushort* xhi = (ushort*)(ws + 3 * (size_t)SEG + TSTATE_F);
    ushort* xlo = xhi + (size_t)SEG;
    ushort* ahi = xhi;  // alias: x dead after gemm_qkv; attn written after
    ushort* alo = xlo;
    ushort* wqthi = xlo + (size_t)SEG;
    ushort* wqtlo = wqthi + (size_t)DIM * NQKV;
    ushort* wothi = wqtlo + (size_t)DIM * NQKV;
    ushort* wotlo = wothi + (size_t)DIM * DIM;
    ushort* qhi = wotlo + (size_t)DIM * DIM;
    ushort* qlo = qhi + (size_t)SEG;
    ushort* kthi = qlo + (size_t)SEG;
    ushort* ktlo = kthi + (size_t)KTSZ;
    ushort* vthi = ktlo + (size_t)KTSZ;
    ushort* vtlo = vthi + (size_t)KTSZ;

    hipLaunchKernelGGL(prep_x_k, dim3(SEG / 1024), dim3(256), 0, stream, x, xhi, xlo);
    hipLaunchKernelGGL(prep_wt_k, dim3(NQKV / 32, DIM / 32), dim3(256), 0, stream,
                       w_qkv, wqthi, wqtlo, DIM, NQKV);
    hipLaunchKernelGGL(prep_wt_k, dim3(DIM / 32, DIM / 32), dim3(256), 0, stream,
                       w_out, wothi, wotlo, DIM, DIM);
    hipLaunchKernelGGL(gemm_qkv_mfma, dim3(NQKV / 64, 2304 / 128), dim3(256), 0, stream,
                       xhi, xlo, wqthi, wqtlo, qh, kh, vh,
                       qhi, qlo, kthi, ktlo, vthi, vtlo);
    hipLaunchKernelGGL(attn_text_mfma, dim3(NBH * 18), dim3(256), 0, stream,
                       qhi, qlo, kthi, ktlo, vthi, vtlo, ahi, alo, tstate);
    hipLaunchKernelGGL(attn_img_k, dim3(NBH * 16), dim3(512), 0, stream,
                       qh, kh, vh, ahi, alo, tstate);
    hipLaunchKernelGGL(gemm_out_mfma, dim3(DIM / 64, 2304 / 128), dim3(256), 0, stream,
                       ahi, alo, wothi, wotlo, b_out, Y);
}

// Round 15
// 125.740 us; speedup vs baseline: 1.0628x; 1.0440x over previous
//
#include <hip/hip_runtime.h>
#include <hip/hip_bf16.h>
#include <math.h>

#define NTOK 1152
#define DIM 512
#define NQKV 1536
#define DHEAD 64
#define NBH 16
#define TEXTN 128
#define IMGLEN 1024
#define SEG (NBH * NTOK * DHEAD)  // 1179648
#define STF 68
#define TSTATE_F (NBH * IMGLEN * STF)
#define LPAD 40
#define KTSZ (NBH * TEXTN * DHEAD)  // 131072

typedef __attribute__((ext_vector_type(8))) short bf16x8;
typedef __attribute__((ext_vector_type(8))) ushort u16x8;
typedef __attribute__((ext_vector_type(4))) float f32x4;

__device__ __forceinline__ ushort f2bf(float f) {
    unsigned u = __float_as_uint(f);
    unsigned r = (u + 0x7FFFu + ((u >> 16) & 1u)) >> 16;  // RNE
    return (ushort)r;
}
__device__ __forceinline__ float bf2f(ushort u) {
    return __uint_as_float(((unsigned)u) << 16);
}

// ---------------- P1: x -> x_hi/x_lo bf16 ---------------------------------
__global__ __launch_bounds__(256) void prep_x_k(const float* __restrict__ X,
                                                ushort* __restrict__ xhi,
                                                ushort* __restrict__ xlo) {
    int i = (blockIdx.x * 256 + threadIdx.x) * 4;
    float4 v = *(const float4*)(X + i);
    ushort4 h, l;
    h.x = f2bf(v.x); l.x = f2bf(v.x - bf2f(h.x));
    h.y = f2bf(v.y); l.y = f2bf(v.y - bf2f(h.y));
    h.z = f2bf(v.z); l.z = f2bf(v.z - bf2f(h.z));
    h.w = f2bf(v.w); l.w = f2bf(v.w - bf2f(h.w));
    *(ushort4*)(xhi + i) = h;
    *(ushort4*)(xlo + i) = l;
}

// ---------------- P2: W[K][N] -> Wt_hi/lo[N][K] bf16 ----------------------
__global__ __launch_bounds__(256) void prep_wt_k(const float* __restrict__ W,
                                                 ushort* __restrict__ thi,
                                                 ushort* __restrict__ tlo,
                                                 int K, int N) {
    __shared__ float tile[32][33];
    const int bx = blockIdx.x, by = blockIdx.y;
    const int c = threadIdx.x & 31, r8 = threadIdx.x >> 5;
#pragma unroll
    for (int i = 0; i < 4; ++i) {
        int rr = r8 + i * 8;
        tile[rr][c] = W[(size_t)(by * 32 + rr) * N + bx * 32 + c];
    }
    __syncthreads();
#pragma unroll
    for (int i = 0; i < 4; ++i) {
        int rr = r8 + i * 8;
        float v = tile[c][rr];
        size_t o = (size_t)(bx * 32 + rr) * K + by * 32 + c;
        ushort h = f2bf(v);
        thi[o] = h;
        tlo[o] = f2bf(v - bf2f(h));
    }
}

// ---------------- K1: qkv GEMM via split-bf16 MFMA ------------------------
// Epilogue now LDS-bounced: acc -> Cb[128][68] -> coalesced row stores.
__global__ __launch_bounds__(256) void gemm_qkv_mfma(const ushort* __restrict__ xhi,
                                                     const ushort* __restrict__ xlo,
                                                     const ushort* __restrict__ wthi,
                                                     const ushort* __restrict__ wtlo,
                                                     float* __restrict__ qh,
                                                     float* __restrict__ kh,
                                                     float* __restrict__ vh,
                                                     ushort* __restrict__ qhi,
                                                     ushort* __restrict__ qlo,
                                                     ushort* __restrict__ kthi,
                                                     ushort* __restrict__ ktlo,
                                                     ushort* __restrict__ vthi,
                                                     ushort* __restrict__ vtlo) {
    __shared__ __align__(16) ushort Ah[128 * LPAD], Al[128 * LPAD];
    __shared__ __align__(16) ushort Bh[64 * LPAD], Bl[64 * LPAD];
    __shared__ __align__(16) float Cb[128 * 68];
    const int tid = threadIdx.x;
    const int lane = tid & 63;
    const int w = tid >> 6;
    const int wm = w >> 1, wn = w & 1;
    const int row0 = blockIdx.y * 128;
    const int col0 = blockIdx.x * 64;

    f32x4 acc[4][2];
#pragma unroll
    for (int a = 0; a < 4; ++a)
#pragma unroll
        for (int b = 0; b < 2; ++b) acc[a][b] = (f32x4){0.f, 0.f, 0.f, 0.f};

    const int arow = tid >> 1;
    const int akb = (tid & 1) * 16;
    const int brow = tid >> 2;
    const int bkb = (tid & 3) * 8;
    const int kf = (lane >> 4) * 8;
    const int lr = lane & 15;
    const int lg = lane >> 4;

    for (int k0 = 0; k0 < DIM; k0 += 32) {
        {
            const size_t g = (size_t)(row0 + arow) * DIM + k0 + akb;
            *(bf16x8*)&Ah[arow * LPAD + akb] = *(const bf16x8*)(xhi + g);
            *(bf16x8*)&Ah[arow * LPAD + akb + 8] = *(const bf16x8*)(xhi + g + 8);
            *(bf16x8*)&Al[arow * LPAD + akb] = *(const bf16x8*)(xlo + g);
            *(bf16x8*)&Al[arow * LPAD + akb + 8] = *(const bf16x8*)(xlo + g + 8);
        }
        {
            const size_t g = (size_t)(col0 + brow) * DIM + k0 + bkb;
            *(bf16x8*)&Bh[brow * LPAD + bkb] = *(const bf16x8*)(wthi + g);
            *(bf16x8*)&Bl[brow * LPAD + bkb] = *(const bf16x8*)(wtlo + g);
        }
        __syncthreads();
        bf16x8 ah[4], al[4], bh[2], bl[2];
#pragma unroll
        for (int mi = 0; mi < 4; ++mi) {
            int rr = wm * 64 + mi * 16 + lr;
            ah[mi] = *(const bf16x8*)&Ah[rr * LPAD + kf];
            al[mi] = *(const bf16x8*)&Al[rr * LPAD + kf];
        }
#pragma unroll
        for (int ni = 0; ni < 2; ++ni) {
            int rr = wn * 32 + ni * 16 + lr;
            bh[ni] = *(const bf16x8*)&Bh[rr * LPAD + kf];
            bl[ni] = *(const bf16x8*)&Bl[rr * LPAD + kf];
        }
#pragma unroll
        for (int mi = 0; mi < 4; ++mi)
#pragma unroll
            for (int ni = 0; ni < 2; ++ni) {
                acc[mi][ni] = __builtin_amdgcn_mfma_f32_16x16x32_bf16(ah[mi], bh[ni], acc[mi][ni], 0, 0, 0);
                acc[mi][ni] = __builtin_amdgcn_mfma_f32_16x16x32_bf16(ah[mi], bl[ni], acc[mi][ni], 0, 0, 0);
                acc[mi][ni] = __builtin_amdgcn_mfma_f32_16x16x32_bf16(al[mi], bh[ni], acc[mi][ni], 0, 0, 0);
            }
        __syncthreads();
    }

    // ---- epilogue: acc -> Cb (LDS) -> coalesced stores ----
#pragma unroll
    for (int mi = 0; mi < 4; ++mi)
#pragma unroll
        for (int ni = 0; ni < 2; ++ni)
#pragma unroll
            for (int j = 0; j < 4; ++j) {
                int lrow = wm * 64 + mi * 16 + lg * 4 + j;
                int lcol = wn * 32 + ni * 16 + lr;
                Cb[lrow * 68 + lcol] = acc[mi][ni][j];
            }
    __syncthreads();

    const int which = col0 >> 9;
    const int hh = (col0 & 511) >> 6;
    const float scale = (which == 0) ? 0.125f : 1.f;
    float* dst = (which == 0) ? qh : ((which == 1) ? kh : vh);

    const int orow = tid >> 1;            // 0..127
    const int och = (tid & 1) * 32;       // col half
    const int r = row0 + orow;
    const int b_i = r / NTOK, tok = r - b_i * NTOK;
    const int bhi = b_i * 8 + hh;

    float vals[32];
#pragma unroll
    for (int g = 0; g < 8; ++g) {
        float4 v = *(const float4*)&Cb[orow * 68 + och + g * 4];
        vals[g * 4] = v.x * scale; vals[g * 4 + 1] = v.y * scale;
        vals[g * 4 + 2] = v.z * scale; vals[g * 4 + 3] = v.w * scale;
    }
    {
        float* dp = dst + ((size_t)bhi * NTOK + tok) * DHEAD + och;
#pragma unroll
        for (int g = 0; g < 8; ++g) {
            float4 o;
            o.x = vals[g * 4]; o.y = vals[g * 4 + 1];
            o.z = vals[g * 4 + 2]; o.w = vals[g * 4 + 3];
            *(float4*)(dp + g * 4) = o;
        }
    }
    if (which == 0) {
        size_t qo = ((size_t)bhi * NTOK + tok) * DHEAD + och;
        u16x8 h8[2], l8[2];
#pragma unroll
        for (int h2 = 0; h2 < 2; ++h2)
#pragma unroll
            for (int e = 0; e < 8; ++e) {
                float v = vals[h2 * 8 + e + (h2 ? 8 : 0)];
                (void)v;
            }
        // build 4 ushort8 pairs (32 elems = 2 x u16x8 per array half)
#pragma unroll
        for (int half = 0; half < 2; ++half) {
            u16x8 hh8, ll8;
#pragma unroll
            for (int e = 0; e < 8; ++e) {
                float v = vals[half * 16 + e];
                ushort hv = f2bf(v);
                hh8[e] = hv; ll8[e] = f2bf(v - bf2f(hv));
            }
            *(u16x8*)(qhi + qo + half * 16) = hh8;
            *(u16x8*)(qlo + qo + half * 16) = ll8;
            u16x8 hh9, ll9;
#pragma unroll
            for (int e = 0; e < 8; ++e) {
                float v = vals[half * 16 + 8 + e];
                ushort hv = f2bf(v);
                hh9[e] = hv; ll9[e] = f2bf(v - bf2f(hv));
            }
            *(u16x8*)(qhi + qo + half * 16 + 8) = hh9;
            *(u16x8*)(qlo + qo + half * 16 + 8) = ll9;
        }
    } else if (tok >= IMGLEN) {
        const int tr = tok - IMGLEN;
        if (which == 1) {
            size_t ko = ((size_t)bhi * TEXTN + tr) * DHEAD + och;
#pragma unroll
            for (int half = 0; half < 4; ++half) {
                u16x8 hh8, ll8;
#pragma unroll
                for (int e = 0; e < 8; ++e) {
                    float v = vals[half * 8 + e];
                    ushort hv = f2bf(v);
                    hh8[e] = hv; ll8[e] = f2bf(v - bf2f(hv));
                }
                *(u16x8*)(kthi + ko + half * 8) = hh8;
                *(u16x8*)(ktlo + ko + half * 8) = ll8;
            }
        } else {
            // V transposed [bh][d][128]: scalar stores (only 16 of 432 blocks)
#pragma unroll
            for (int e = 0; e < 32; ++e) {
                int d = och + e;
                size_t vo = ((size_t)bhi * DHEAD + d) * TEXTN + tr;
                ushort hv = f2bf(vals[e]);
                vthi[vo] = hv;
                vtlo[vo] = f2bf(vals[e] - bf2f(hv));
            }
        }
    }
}

// ---------------- K2: text-key attention via MFMA (all 1152 rows) ---------
__global__ __launch_bounds__(256) void attn_text_mfma(const ushort* __restrict__ qhi,
                                                      const ushort* __restrict__ qlo,
                                                      const ushort* __restrict__ kthi,
                                                      const ushort* __restrict__ ktlo,
                                                      const ushort* __restrict__ vthi,
                                                      const ushort* __restrict__ vtlo,
                                                      ushort* __restrict__ ahi,
                                                      ushort* __restrict__ alo,
                                                      float* __restrict__ tstate) {
    __shared__ __align__(16) ushort Phi[4][16][136];
    __shared__ __align__(16) ushort Plo[4][16][136];
    const int bh = blockIdx.x / 18;
    const int tile = blockIdx.x % 18;
    const int wave = threadIdx.x >> 6;
    const int lane = threadIdx.x & 63;
    const int lr = lane & 15, lg = lane >> 4;
    const int kf = lg * 8;
    const int qrow0 = tile * 64 + wave * 16;
    const int tok0 = (tile < 2 ? 1024 + tile * 64 : tile * 64) + wave * 16;

    bf16x8 qah[2], qal[2];
    {
        const size_t qb = ((size_t)bh * NTOK + tok0 + lr) * DHEAD;
#pragma unroll
        for (int c = 0; c < 2; ++c) {
            qah[c] = *(const bf16x8*)(qhi + qb + c * 32 + kf);
            qal[c] = *(const bf16x8*)(qlo + qb + c * 32 + kf);
        }
    }
    f32x4 s[8];
#pragma unroll
    for (int t = 0; t < 8; ++t) s[t] = (f32x4){0.f, 0.f, 0.f, 0.f};
#pragma unroll
    for (int t = 0; t < 8; ++t) {
        const size_t kb = ((size_t)bh * TEXTN + t * 16 + lr) * DHEAD;
#pragma unroll
        for (int c = 0; c < 2; ++c) {
            bf16x8 kbh = *(const bf16x8*)(kthi + kb + c * 32 + kf);
            bf16x8 kbl = *(const bf16x8*)(ktlo + kb + c * 32 + kf);
            s[t] = __builtin_amdgcn_mfma_f32_16x16x32_bf16(qah[c], kbh, s[t], 0, 0, 0);
            s[t] = __builtin_amdgcn_mfma_f32_16x16x32_bf16(qah[c], kbl, s[t], 0, 0, 0);
            s[t] = __builtin_amdgcn_mfma_f32_16x16x32_bf16(qal[c], kbh, s[t], 0, 0, 0);
        }
    }
    float mx[4], sm[4];
#pragma unroll
    for (int r = 0; r < 4; ++r) {
        float v = s[0][r];
#pragma unroll
        for (int t = 1; t < 8; ++t) v = fmaxf(v, s[t][r]);
        mx[r] = v;
    }
#pragma unroll
    for (int msk = 1; msk <= 8; msk <<= 1)
#pragma unroll
        for (int r = 0; r < 4; ++r) mx[r] = fmaxf(mx[r], __shfl_xor(mx[r], msk));
#pragma unroll
    for (int r = 0; r < 4; ++r) sm[r] = 0.f;
#pragma unroll
    for (int t = 0; t < 8; ++t)
#pragma unroll
        for (int r = 0; r < 4; ++r) {
            float p = __expf(s[t][r] - mx[r]);
            s[t][r] = p;
            sm[r] += p;
        }
#pragma unroll
    for (int msk = 1; msk <= 8; msk <<= 1)
#pragma unroll
        for (int r = 0; r < 4; ++r) sm[r] += __shfl_xor(sm[r], msk);
#pragma unroll
    for (int t = 0; t < 8; ++t)
#pragma unroll
        for (int r = 0; r < 4; ++r) {
            float p = s[t][r];
            ushort h = f2bf(p);
            Phi[wave][lg * 4 + r][t * 16 + lr] = h;
            Plo[wave][lg * 4 + r][t * 16 + lr] = f2bf(p - bf2f(h));
        }
    __syncthreads();
    f32x4 o[4];
#pragma unroll
    for (int dt = 0; dt < 4; ++dt) o[dt] = (f32x4){0.f, 0.f, 0.f, 0.f};
#pragma unroll
    for (int c = 0; c < 4; ++c) {
        bf16x8 pah = *(const bf16x8*)&Phi[wave][lr][c * 32 + kf];
        bf16x8 pal = *(const bf16x8*)&Plo[wave][lr][c * 32 + kf];
#pragma unroll
        for (int dt = 0; dt < 4; ++dt) {
            const size_t vb = ((size_t)bh * DHEAD + dt * 16 + lr) * TEXTN + c * 32 + kf;
            bf16x8 vbh = *(const bf16x8*)(vthi + vb);
            bf16x8 vbl = *(const bf16x8*)(vtlo + vb);
            o[dt] = __builtin_amdgcn_mfma_f32_16x16x32_bf16(pah, vbh, o[dt], 0, 0, 0);
            o[dt] = __builtin_amdgcn_mfma_f32_16x16x32_bf16(pah, vbl, o[dt], 0, 0, 0);
            o[dt] = __builtin_amdgcn_mfma_f32_16x16x32_bf16(pal, vbh, o[dt], 0, 0, 0);
        }
    }
    if (tile < 2) {
#pragma unroll
        for (int r = 0; r < 4; ++r) {
            const int row = qrow0 + lg * 4 + r;
            const float inv = 1.f / sm[r];
            const size_t base = ((size_t)bh * NTOK + row) * DHEAD;
#pragma unroll
            for (int dt = 0; dt < 4; ++dt) {
                float v = o[dt][r] * inv;
                ushort h = f2bf(v);
                ahi[base + dt * 16 + lr] = h;
                alo[base + dt * 16 + lr] = f2bf(v - bf2f(h));
            }
        }
    } else {
#pragma unroll
        for (int r = 0; r < 4; ++r) {
            const int imgq = qrow0 - TEXTN + lg * 4 + r;
            float* st = tstate + ((size_t)bh * IMGLEN + imgq) * STF;
#pragma unroll
            for (int dt = 0; dt < 4; ++dt) st[dt * 16 + lr] = o[dt][r];
            if (lr == 0) { st[64] = mx[r]; st[65] = sm[r]; }
        }
    }
}

// ---------------- K3: img local 25-slot part, LDS-staged K/V --------------
template <int W8>
__device__ inline void loc_dots8_lds(const float* __restrict__ Kl, int yloc, int x, int y,
                                     const float (&q)[64], float (&sd)[25]) {
#pragma unroll
    for (int t = 0; t < 25; ++t) {
        const int ny = y + t / 5 - 2;
        const int nx = x + t % 5 - 2;
        if (ny >= 0 && ny < 32 && nx >= 0 && nx < 32) {
            const int px = (yloc + t / 5) * 32 + nx;
            const float* base = Kl + px * 64;
            float4 k0 = *(const float4*)(base + (((2 * W8) ^ (px & 7)) << 2));
            float4 k1 = *(const float4*)(base + (((2 * W8 + 1) ^ (px & 7)) << 2));
            float ke[8] = {k0.x, k0.y, k0.z, k0.w, k1.x, k1.y, k1.z, k1.w};
#pragma unroll
            for (int e = 0; e < 8; ++e) {
                const int d = W8 * 8 + e;
                const int id2 = d * 25 + t;
                sd[id2 >> 6] += q[id2 & 63] * ke[e];
            }
        }
    }
}

template <int W, int T0, int T1>
__device__ inline void loc_pvr_lds(const float* __restrict__ Vl, int yloc, int x, int y,
                                   const float (&pp)[25], float (&po)[64]) {
#pragma unroll
    for (int t = T0; t < T1; ++t) {
        const int ny = y + t / 5 - 2;
        const int nx = x + t % 5 - 2;
        if (ny >= 0 && ny < 32 && nx >= 0 && nx < 32) {
            const int px = (yloc + t / 5) * 32 + nx;
            const float* base = Vl + px * 64;
#pragma unroll
            for (int g = 0; g < 4; ++g) {
                float4 vv = *(const float4*)(base + (((4 * W + g) ^ (px & 7)) << 2));
                float ve[4] = {vv.x, vv.y, vv.z, vv.w};
#pragma unroll
                for (int e = 0; e < 4; ++e) {
                    const int d = W * 16 + g * 4 + e;
                    const int id2 = d * 25 + t;
                    po[id2 & 63] += pp[id2 >> 6] * ve[e];
                }
            }
        }
    }
}

__global__ __launch_bounds__(512, 1) void attn_img_k(const float* __restrict__ qh,
                                                     const float* __restrict__ kh,
                                                     const float* __restrict__ vh,
                                                     ushort* __restrict__ ahi,
                                                     ushort* __restrict__ alo,
                                                     const float* __restrict__ tstate) {
    __shared__ __align__(16) float smem[8 * 64 * 26];  // 53248 B: qbuf then sdb; pob aliases
    __shared__ __align__(16) float Kl[192 * 64];       // 49152 B
    __shared__ __align__(16) float Vl[192 * 64];       // 49152 B
    float (*sdb)[64][26] = reinterpret_cast<float (*)[64][26]>(smem);   // [8]
    float (*pob)[64][68] = reinterpret_cast<float (*)[64][68]>(smem);   // [2]
    const int bh = blockIdx.x >> 4;
    const int qtile = (blockIdx.x & 15) << 6;
    const int yr0 = qtile >> 5;
    const int wave = threadIdx.x >> 6;
    const int lane = threadIdx.x & 63;
    const int qq = qtile + lane;
    const int y = qq >> 5, x = qq & 31;
    const int yloc = lane >> 5;
    const float* kimg = kh + (size_t)(bh * NTOK + TEXTN) * DHEAD;
    const float* vimg = vh + (size_t)(bh * NTOK + TEXTN) * DHEAD;
    const float* st = tstate + ((size_t)(bh * IMGLEN + qq)) * STF;

#pragma unroll
    for (int i = 0; i < 6; ++i) {
        int flat = threadIdx.x + i * 512;
        int px = flat >> 4, b = flat & 15;
        int gy = yr0 - 2 + (px >> 5), gx = px & 31;
        if (gy >= 0 && gy < 32) {
            size_t off = ((size_t)(gy * 32 + gx)) * DHEAD + b * 4;
            int dsto = px * 64 + ((b ^ (px & 7)) << 2);
            *(float4*)&Kl[dsto] = *(const float4*)(kimg + off);
            *(float4*)&Vl[dsto] = *(const float4*)(vimg + off);
        }
    }
    {
        const float* qbase = qh + ((size_t)(bh * NTOK + TEXTN + qtile)) * DHEAD;
#pragma unroll
        for (int i = 0; i < 2; ++i) {
            int flat = threadIdx.x + i * 512;
            int px = flat >> 4, b = flat & 15;
            *(float4*)&smem[px * 64 + ((b ^ (px & 7)) << 2)] =
                *(const float4*)(qbase + (size_t)px * DHEAD + b * 4);
        }
    }
    __syncthreads();

    float q[64];
#pragma unroll
    for (int b = 0; b < 16; ++b) {
        float4 v = *(const float4*)&smem[lane * 64 + ((b ^ (lane & 7)) << 2)];
        q[b * 4] = v.x; q[b * 4 + 1] = v.y; q[b * 4 + 2] = v.z; q[b * 4 + 3] = v.w;
    }
    __syncthreads();

    float sd[25];
#pragma unroll
    for (int j = 0; j < 25; ++j) sd[j] = 0.f;
    switch (wave) {
        case 0: loc_dots8_lds<0>(Kl, yloc, x, y, q, sd); break;
        case 1: loc_dots8_lds<1>(Kl, yloc, x, y, q, sd); break;
        case 2: loc_dots8_lds<2>(Kl, yloc, x, y, q, sd); break;
        case 3: loc_dots8_lds<3>(Kl, yloc, x, y, q, sd); break;
        case 4: loc_dots8_lds<4>(Kl, yloc, x, y, q, sd); break;
        case 5: loc_dots8_lds<5>(Kl, yloc, x, y, q, sd); break;
        case 6: loc_dots8_lds<6>(Kl, yloc, x, y, q, sd); break;
        default: loc_dots8_lds<7>(Kl, yloc, x, y, q, sd); break;
    }
#pragma unroll
    for (int j = 0; j < 25; ++j) sdb[wave][lane][j] = sd[j];
    __syncthreads();

    float p[25];
#pragma unroll
    for (int j = 0; j < 25; ++j)
        p[j] = ((sdb[0][lane][j] + sdb[1][lane][j]) + (sdb[2][lane][j] + sdb[3][lane][j])) +
               ((sdb[4][lane][j] + sdb[5][lane][j]) + (sdb[6][lane][j] + sdb[7][lane][j]));
    float m = st[64], l = st[65];
    float mloc = -1e30f;
#pragma unroll
    for (int j = 0; j < 25; ++j) {
        const int my = y + j / 5 - 2;
        const int mx2 = x + j % 5 - 2;
        bool inb = (my >= 0 && my < 32 && mx2 >= 0 && mx2 < 32);
        bool keep = inb ? (qq <= my * 32 + mx2) : true;
        p[j] = keep ? p[j] : -1e30f;
        mloc = fmaxf(mloc, p[j]);
    }
    const float M = fmaxf(m, mloc);
    const float cc = __expf(m - M);
    l *= cc;
#pragma unroll
    for (int j = 0; j < 25; ++j) {
        p[j] = __expf(p[j] - M);
        l += p[j];
    }
    const float inv = 1.f / l;

    float po[64];
#pragma unroll
    for (int o = 0; o < 64; ++o) po[o] = 0.f;
    switch (wave) {
        case 0: loc_pvr_lds<0, 0, 13>(Vl, yloc, x, y, p, po); break;
        case 1: loc_pvr_lds<1, 0, 13>(Vl, yloc, x, y, p, po); break;
        case 2: loc_pvr_lds<2, 0, 13>(Vl, yloc, x, y, p, po); break;
        case 3: loc_pvr_lds<3, 0, 13>(Vl, yloc, x, y, p, po); break;
        case 4: loc_pvr_lds<0, 13, 25>(Vl, yloc, x, y, p, po); break;
        case 5: loc_pvr_lds<1, 13, 25>(Vl, yloc, x, y, p, po); break;
        case 6: loc_pvr_lds<2, 13, 25>(Vl, yloc, x, y, p, po); break;
        default: loc_pvr_lds<3, 13, 25>(Vl, yloc, x, y, p, po); break;
    }
    __syncthreads();

    if (wave < 2) {
#pragma unroll
        for (int o = 0; o < 64; ++o) pob[wave][lane][o] = po[o];
    }
    __syncthreads();
    if (wave >= 2 && wave < 4) {
#pragma unroll
        for (int o = 0; o < 64; ++o) pob[wave - 2][lane][o] += po[o];
    }
    __syncthreads();
    if (wave >= 4 && wave < 6) {
#pragma unroll
        for (int o = 0; o < 64; ++o) pob[wave - 4][lane][o] += po[o];
    }
    __syncthreads();
    if (wave >= 6) {
#pragma unroll
        for (int o = 0; o < 64; ++o) pob[wave - 6][lane][o] += po[o];
    }
    __syncthreads();

    if (wave < 4) {
        const float* stq = st + wave * 16;
        size_t base = ((size_t)(bh * NTOK + TEXTN + qq)) * DHEAD + wave * 16;
#pragma unroll
        for (int g = 0; g < 4; ++g) {
            float4 tv = *(const float4*)(stq + g * 4);
            float4 a0 = *(const float4*)&pob[0][lane][wave * 16 + g * 4];
            float4 a1 = *(const float4*)&pob[1][lane][wave * 16 + g * 4];
            float v0 = (a0.x + a1.x + cc * tv.x) * inv;
            float v1 = (a0.y + a1.y + cc * tv.y) * inv;
            float v2 = (a0.z + a1.z + cc * tv.z) * inv;
            float v3 = (a0.w + a1.w + cc * tv.w) * inv;
            ushort4 oh, ol;
            oh.x = f2bf(v0); ol.x = f2bf(v0 - bf2f(oh.x));
            oh.y = f2bf(v1); ol.y = f2bf(v1 - bf2f(oh.y));
            oh.z = f2bf(v2); ol.z = f2bf(v2 - bf2f(oh.z));
            oh.w = f2bf(v3); ol.w = f2bf(v3 - bf2f(oh.w));
            *(ushort4*)(ahi + base + g * 4) = oh;
            *(ushort4*)(alo + base + g * 4) = ol;
        }
    }
}

// ---------------- K4: out GEMM via split-bf16 MFMA ------------------------
// Epilogue LDS-bounced: acc -> Cb -> coalesced float4 stores.
__global__ __launch_bounds__(256) void gemm_out_mfma(const ushort* __restrict__ ahi,
                                                     const ushort* __restrict__ alo,
                                                     const ushort* __restrict__ wthi,
                                                     const ushort* __restrict__ wtlo,
                                                     const float* __restrict__ bias,
                                                     float* __restrict__ Y) {
    __shared__ __align__(16) ushort Ah[128 * LPAD], Al[128 * LPAD];
    __shared__ __align__(16) ushort Bh[64 * LPAD], Bl[64 * LPAD];
    __shared__ __align__(16) float Cb[128 * 68];
    const int tid = threadIdx.x;
    const int lane = tid & 63;
    const int w = tid >> 6;
    const int wm = w >> 1, wn = w & 1;
    const int row0 = blockIdx.y * 128;
    const int col0 = blockIdx.x * 64;

    f32x4 acc[4][2];
#pragma unroll
    for (int a = 0; a < 4; ++a)
#pragma unroll
        for (int b = 0; b < 2; ++b) acc[a][b] = (f32x4){0.f, 0.f, 0.f, 0.f};

    const int arow = tid >> 1;
    const int akb = (tid & 1) * 16;
    const int brow = tid >> 2;
    const int bkb = (tid & 3) * 8;
    const int kf = (lane >> 4) * 8;
    const int lr = lane & 15;
    const int lg = lane >> 4;

    const int ar = row0 + arow;
    const int a_bi = ar / NTOK;
    const int a_tok = ar - a_bi * NTOK;

    for (int k0 = 0; k0 < DIM; k0 += 32) {
        {
            const int kg = k0 + akb;
            const int hh = kg >> 6, d0 = kg & 63;
            const size_t g = ((size_t)(a_bi * 8 + hh) * NTOK + a_tok) * DHEAD + d0;
            *(bf16x8*)&Ah[arow * LPAD + akb] = *(const bf16x8*)(ahi + g);
            *(bf16x8*)&Ah[arow * LPAD + akb + 8] = *(const bf16x8*)(ahi + g + 8);
            *(bf16x8*)&Al[arow * LPAD + akb] = *(const bf16x8*)(alo + g);
            *(bf16x8*)&Al[arow * LPAD + akb + 8] = *(const bf16x8*)(alo + g + 8);
        }
        {
            const size_t g = (size_t)(col0 + brow) * DIM + k0 + bkb;
            *(bf16x8*)&Bh[brow * LPAD + bkb] = *(const bf16x8*)(wthi + g);
            *(bf16x8*)&Bl[brow * LPAD + bkb] = *(const bf16x8*)(wtlo + g);
        }
        __syncthreads();
        bf16x8 ah[4], al[4], bh[2], bl[2];
#pragma unroll
        for (int mi = 0; mi < 4; ++mi) {
            int rr = wm * 64 + mi * 16 + lr;
            ah[mi] = *(const bf16x8*)&Ah[rr * LPAD + kf];
            al[mi] = *(const bf16x8*)&Al[rr * LPAD + kf];
        }
#pragma unroll
        for (int ni = 0; ni < 2; ++ni) {
            int rr = wn * 32 + ni * 16 + lr;
            bh[ni] = *(const bf16x8*)&Bh[rr * LPAD + kf];
            bl[ni] = *(const bf16x8*)&Bl[rr * LPAD + kf];
        }
#pragma unroll
        for (int mi = 0; mi < 4; ++mi)
#pragma unroll
            for (int ni = 0; ni < 2; ++ni) {
                acc[mi][ni] = __builtin_amdgcn_mfma_f32_16x16x32_bf16(ah[mi], bh[ni], acc[mi][ni], 0, 0, 0);
                acc[mi][ni] = __builtin_amdgcn_mfma_f32_16x16x32_bf16(ah[mi], bl[ni], acc[mi][ni], 0, 0, 0);
                acc[mi][ni] = __builtin_amdgcn_mfma_f32_16x16x32_bf16(al[mi], bh[ni], acc[mi][ni], 0, 0, 0);
            }
        __syncthreads();
    }

    // ---- epilogue: acc -> Cb -> coalesced stores ----
#pragma unroll
    for (int mi = 0; mi < 4; ++mi)
#pragma unroll
        for (int ni = 0; ni < 2; ++ni)
#pragma unroll
            for (int j = 0; j < 4; ++j) {
                int lrow = wm * 64 + mi * 16 + lg * 4 + j;
                int lcol = wn * 32 + ni * 16 + lr;
                Cb[lrow * 68 + lcol] = acc[mi][ni][j];
            }
    __syncthreads();

    const int orow = tid >> 1;
    const int och = (tid & 1) * 32;
    const int r = row0 + orow;
    float* yp = Y + (size_t)r * DIM + col0 + och;
    const float* bp = bias + col0 + och;
#pragma unroll
    for (int g = 0; g < 8; ++g) {
        float4 v = *(const float4*)&Cb[orow * 68 + och + g * 4];
        float4 b = *(const float4*)(bp + g * 4);
        float4 o;
        o.x = v.x + b.x; o.y = v.y + b.y; o.z = v.z + b.z; o.w = v.w + b.w;
        *(float4*)(yp + g * 4) = o;
    }
}

extern "C" void kernel_launch(void* const* d_in, const int* in_sizes, int n_in,
                              void* d_out, int out_size, void* d_ws, size_t ws_size,
                              hipStream_t stream) {
    const float* x = (const float*)d_in[0];
    const float* w_qkv = (const float*)d_in[1];
    const float* w_out = (const float*)d_in[2];
    const float* b_out = (const float*)d_in[3];
    float* Y = (float*)d_out;
    float* ws = (float*)d_ws;
    float* qh = ws;
    float* kh = ws + (size_t)SEG;
    float* vh = ws + 2 * (size_t)SEG;
    float* tstate = ws + 3 * (size_t)SEG;
    ushort* xhi = (ushort*)(ws + 3 * (size_t)SEG + TSTATE_F);
    ushort* xlo = xhi + (size_t)SEG;
    ushort* ahi = xhi;  // alias: x dead after gemm_qkv; attn written after
    ushort* alo = xlo;
    ushort* wqthi = xlo + (size_t)SEG;
    ushort* wqtlo = wqthi + (size_t)DIM * NQKV;
    ushort* wothi = wqtlo + (size_t)DIM * NQKV;
    ushort* wotlo = wothi + (size_t)DIM * DIM;
    ushort* qhi = wotlo + (size_t)DIM * DIM;
    ushort* qlo = qhi + (size_t)SEG;
    ushort* kthi = qlo + (size_t)SEG;
    ushort* ktlo = kthi + (size_t)KTSZ;
    ushort* vthi = ktlo + (size_t)KTSZ;
    ushort* vtlo = vthi + (size_t)KTSZ;

    hipLaunchKernelGGL(prep_x_k, dim3(SEG / 1024), dim3(256), 0, stream, x, xhi, xlo);
    hipLaunchKernelGGL(prep_wt_k, dim3(NQKV / 32, DIM / 32), dim3(256), 0, stream,
                       w_qkv, wqthi, wqtlo, DIM, NQKV);
    hipLaunchKernelGGL(prep_wt_k, dim3(DIM / 32, DIM / 32), dim3(256), 0, stream,
                       w_out, wothi, wotlo, DIM, DIM);
    hipLaunchKernelGGL(gemm_qkv_mfma, dim3(NQKV / 64, 2304 / 128), dim3(256), 0, stream,
                       xhi, xlo, wqthi, wqtlo, qh, kh, vh,
                       qhi, qlo, kthi, ktlo, vthi, vtlo);
    hipLaunchKernelGGL(attn_text_mfma, dim3(NBH * 18), dim3(256), 0, stream,
                       qhi, qlo, kthi, ktlo, vthi, vtlo, ahi, alo, tstate);
    hipLaunchKernelGGL(attn_img_k, dim3(NBH * 16), dim3(512), 0, stream,
                       qh, kh, vh, ahi, alo, tstate);
    hipLaunchKernelGGL(gemm_out_mfma, dim3(DIM / 64, 2304 / 128), dim3(256), 0, stream,
                       ahi, alo, wothi, wotlo, b_out, Y);
}